// Round 1
// baseline (805.573 us; speedup 1.0000x reference)
//
#include <hip/hip_runtime.h>
#include <hip/hip_bf16.h>

#define NPAT 50000
#define NCON 20000
#define NN   70000
#define EE   800000
#define H    128

// ---------------- CSR build ----------------

__global__ void hist_kernel(const int* __restrict__ dst, int* __restrict__ deg, int n) {
    int i = blockIdx.x * blockDim.x + threadIdx.x;
    if (i < n) atomicAdd(&deg[dst[i]], 1);
}

// one block per relation; block = 1024 threads; sequential-chunk + block scan
__global__ __launch_bounds__(1024) void exscan2_kernel(
        const int* __restrict__ deg0, int n0, int* __restrict__ offs0,
        const int* __restrict__ deg1, int n1, int* __restrict__ offs1) {
    const int* deg = (blockIdx.x == 0) ? deg0 : deg1;
    int n          = (blockIdx.x == 0) ? n0 : n1;
    int* offs      = (blockIdx.x == 0) ? offs0 : offs1;
    int t = threadIdx.x;
    int per = (n + 1023) >> 10;
    int beg = t * per;
    int end = min(beg + per, n);
    int s = 0;
    for (int i = beg; i < end; i++) s += deg[i];
    __shared__ int sm[1024];
    sm[t] = s;
    __syncthreads();
    for (int d = 1; d < 1024; d <<= 1) {
        int v = (t >= d) ? sm[t - d] : 0;
        __syncthreads();
        sm[t] += v;
        __syncthreads();
    }
    int run = sm[t] - s;  // exclusive prefix
    for (int i = beg; i < end; i++) { offs[i] = run; run += deg[i]; }
    if (t == 1023) offs[n] = sm[1023];
}

__global__ void fill_kernel(const int* __restrict__ dst, const int* __restrict__ src,
                            int* __restrict__ cur, int* __restrict__ esrc, int n) {
    int i = blockIdx.x * blockDim.x + threadIdx.x;
    if (i < n) {
        int p = atomicAdd(&cur[dst[i]], 1);
        esrc[p] = src[i];
    }
}

// ---------------- mean aggregation (gather, CSR) ----------------
// block = 128 threads = 2 waves; lane group g=tid>>5 handles edges j=beg+g, beg+g+4, ...
// each lane reads float4 (cols 4c..4c+3); LDS reduce over the 4 groups.
__global__ __launch_bounds__(128) void aggregate_kernel(
        const float* __restrict__ xbase,   // base so that esrc values index rows directly
        const int* __restrict__ offs, const int* __restrict__ esrc,
        float* __restrict__ out) {
    int d = blockIdx.x;
    int beg = offs[d], end = offs[d + 1];
    int tid = threadIdx.x;
    int g = tid >> 5, c = tid & 31;
    float4 acc = make_float4(0.f, 0.f, 0.f, 0.f);
    for (int j = beg + g; j < end; j += 4) {
        int s = esrc[j];
        const float4 v = *(const float4*)&xbase[(size_t)s * H + c * 4];
        acc.x += v.x; acc.y += v.y; acc.z += v.z; acc.w += v.w;
    }
    __shared__ float4 sm[128];
    sm[tid] = acc;
    __syncthreads();
    if (tid < 32) {
        float4 a = sm[tid], b = sm[tid + 32], e = sm[tid + 64], f = sm[tid + 96];
        float inv = 1.0f / (float)max(end - beg, 1);
        float4 o;
        o.x = (a.x + b.x + e.x + f.x) * inv;
        o.y = (a.y + b.y + e.y + f.y) * inv;
        o.z = (a.z + b.z + e.z + f.z) * inv;
        o.w = (a.w + b.w + e.w + f.w) * inv;
        *(float4*)&out[(size_t)d * H + tid * 4] = o;
    }
}

// ---------------- fused fp32 GEMM: C = [A1 | A2] @ [B1 ; B2] + bias, optional relu ----
// BM=128 rows/block, BN=128 (=H), BK=8. 256 threads, 8x8 microtile per thread.
#define BM 128
#define BK 8

__global__ void gemm128_kernel(
        const float* __restrict__ A1, int lda1, int K1,
        const float* __restrict__ A2, int lda2, int K2,
        const float* __restrict__ B1, const float* __restrict__ B2,  // [K1,128],[K2,128]
        const float* __restrict__ bias,
        float* __restrict__ C, int M, int relu) {
    __shared__ float sA[BK][BM];
    __shared__ float sB[BK][H];
    int tid = threadIdx.x;
    int bm = blockIdx.x * BM;
    // staging indices
    int am = tid >> 1;           // 0..127 (row within tile)
    int ak = (tid & 1) * 4;      // 0 or 4
    int bk = tid >> 5;           // 0..7
    int bn = (tid & 31) * 4;     // 0..124
    // compute indices
    int ty = tid >> 4;           // 0..15 -> rows ty*8 .. ty*8+7
    int tx = tid & 15;           // cols tx*4..tx*4+3 and 64+tx*4..+3
    float acc[8][8] = {};
    int Ktot = K1 + K2;
    for (int k0 = 0; k0 < Ktot; k0 += BK) {
        const float* As; int ldA; int kk; const float* Bs;
        if (k0 < K1) { As = A1; ldA = lda1; kk = k0;      Bs = B1 + (size_t)k0 * H; }
        else         { As = A2; ldA = lda2; kk = k0 - K1; Bs = B2 + (size_t)(k0 - K1) * H; }
        int gm = bm + am; if (gm >= M) gm = M - 1;
        float4 av = *(const float4*)&As[(size_t)gm * ldA + kk + ak];
        float4 bv = *(const float4*)&Bs[bk * H + bn];
        __syncthreads();
        sA[ak + 0][am] = av.x; sA[ak + 1][am] = av.y;
        sA[ak + 2][am] = av.z; sA[ak + 3][am] = av.w;
        *(float4*)&sB[bk][bn] = bv;
        __syncthreads();
#pragma unroll
        for (int k = 0; k < BK; k++) {
            float a[8], b[8];
            *(float4*)&a[0] = *(const float4*)&sA[k][ty * 8];
            *(float4*)&a[4] = *(const float4*)&sA[k][ty * 8 + 4];
            *(float4*)&b[0] = *(const float4*)&sB[k][tx * 4];
            *(float4*)&b[4] = *(const float4*)&sB[k][64 + tx * 4];
#pragma unroll
            for (int i = 0; i < 8; i++)
#pragma unroll
                for (int j = 0; j < 8; j++)
                    acc[i][j] += a[i] * b[j];
        }
    }
    float bcol[8];
    *(float4*)&bcol[0] = *(const float4*)&bias[tx * 4];
    *(float4*)&bcol[4] = *(const float4*)&bias[64 + tx * 4];
#pragma unroll
    for (int i = 0; i < 8; i++) {
        int gr = bm + ty * 8 + i;
        if (gr < M) {
            float4 o1, o2;
            o1.x = acc[i][0] + bcol[0]; o1.y = acc[i][1] + bcol[1];
            o1.z = acc[i][2] + bcol[2]; o1.w = acc[i][3] + bcol[3];
            o2.x = acc[i][4] + bcol[4]; o2.y = acc[i][5] + bcol[5];
            o2.z = acc[i][6] + bcol[6]; o2.w = acc[i][7] + bcol[7];
            if (relu) {
                o1.x = fmaxf(o1.x, 0.f); o1.y = fmaxf(o1.y, 0.f);
                o1.z = fmaxf(o1.z, 0.f); o1.w = fmaxf(o1.w, 0.f);
                o2.x = fmaxf(o2.x, 0.f); o2.y = fmaxf(o2.y, 0.f);
                o2.z = fmaxf(o2.z, 0.f); o2.w = fmaxf(o2.w, 0.f);
            }
            *(float4*)&C[(size_t)gr * H + tx * 4] = o1;
            *(float4*)&C[(size_t)gr * H + 64 + tx * 4] = o2;
        }
    }
}

// ---------------- launch ----------------

extern "C" void kernel_launch(void* const* d_in, const int* in_sizes, int n_in,
                              void* d_out, int out_size, void* d_ws, size_t ws_size,
                              hipStream_t stream) {
    const float* x_patient = (const float*)d_in[0];
    const float* x_concept = (const float*)d_in[1];
    const float* W_p       = (const float*)d_in[2];
    const float* b_p       = (const float*)d_in[3];
    const float* W_c       = (const float*)d_in[4];
    const float* b_c       = (const float*)d_in[5];
    const float* W_root    = (const float*)d_in[6];
    const float* b_root    = (const float*)d_in[7];
    const float* W_rel     = (const float*)d_in[8];
    const int*   src_pc    = (const int*)d_in[9];
    const int*   dst_pc    = (const int*)d_in[10];
    const int*   src_cp    = (const int*)d_in[11];
    const int*   dst_cp    = (const int*)d_in[12];
    float* out = (float*)d_out;

    char* w = (char*)d_ws;
    float* x0    = (float*)w; w += (size_t)NN * H * 4;
    float* aggn0 = (float*)w; w += (size_t)NCON * H * 4;   // concept dst (rel 0: p->c)
    float* aggn1 = (float*)w; w += (size_t)NPAT * H * 4;   // patient dst (rel 1: c->p)
    int* deg0  = (int*)w; w += (size_t)NCON * 4;
    int* deg1  = (int*)w; w += (size_t)NPAT * 4;
    int* offs0 = (int*)w; w += (size_t)(NCON + 1) * 4;
    int* offs1 = (int*)w; w += (size_t)(NPAT + 1) * 4;
    int* cur0  = (int*)w; w += (size_t)NCON * 4;
    int* cur1  = (int*)w; w += (size_t)NPAT * 4;
    int* esrc0 = (int*)w; w += (size_t)EE * 4;
    int* esrc1 = (int*)w; w += (size_t)EE * 4;

    // ---- CSR build (per call; edges are static but no cross-call state allowed)
    hipMemsetAsync(deg0, 0, (size_t)(NCON + NPAT) * 4, stream);  // deg0,deg1 contiguous
    int eb = (EE + 255) / 256;
    hist_kernel<<<eb, 256, 0, stream>>>(dst_pc, deg0, EE);
    hist_kernel<<<eb, 256, 0, stream>>>(dst_cp, deg1, EE);
    exscan2_kernel<<<2, 1024, 0, stream>>>(deg0, NCON, offs0, deg1, NPAT, offs1);
    hipMemcpyAsync(cur0, offs0, (size_t)NCON * 4, hipMemcpyDeviceToDevice, stream);
    hipMemcpyAsync(cur1, offs1, (size_t)NPAT * 4, hipMemcpyDeviceToDevice, stream);
    fill_kernel<<<eb, 256, 0, stream>>>(dst_pc, src_pc, cur0, esrc0, EE);
    fill_kernel<<<eb, 256, 0, stream>>>(dst_cp, src_cp, cur1, esrc1, EE);

    // ---- projections -> x0 (patients rows 0..NPAT, concepts NPAT..NN)
    gemm128_kernel<<<(NPAT + BM - 1) / BM, 256, 0, stream>>>(
        x_patient, 64, 64, nullptr, 0, 0, W_p, nullptr, b_p, x0, NPAT, 0);
    gemm128_kernel<<<(NCON + BM - 1) / BM, 256, 0, stream>>>(
        x_concept, 128, 128, nullptr, 0, 0, W_c, nullptr, b_c,
        x0 + (size_t)NPAT * H, NCON, 0);

    // ---- layers
    const float* xin = x0;
    float* xout = out;          // layer 0 output -> d_out; layer 1 output -> x0
    for (int l = 0; l < 2; l++) {
        // rel0 (p->c): src are global patient rows; dst concepts
        aggregate_kernel<<<NCON, 128, 0, stream>>>(xin, offs0, esrc0, aggn0);
        // rel1 (c->p): src are concept-local rows -> base xin + NPAT*H
        aggregate_kernel<<<NPAT, 128, 0, stream>>>(xin + (size_t)NPAT * H, offs1, esrc1, aggn1);

        const float* Wroot_l = W_root + (size_t)l * H * H;
        const float* Wrel_l0 = W_rel + (size_t)(l * 2 + 0) * H * H;
        const float* Wrel_l1 = W_rel + (size_t)(l * 2 + 1) * H * H;
        const float* br = b_root + (size_t)l * H;

        // patients: out = x@Wroot + aggn1@Wrel[l,1] + b, relu
        gemm128_kernel<<<(NPAT + BM - 1) / BM, 256, 0, stream>>>(
            xin, H, H, aggn1, H, H, Wroot_l, Wrel_l1, br, xout, NPAT, 1);
        // concepts: out = x@Wroot + aggn0@Wrel[l,0] + b, relu
        gemm128_kernel<<<(NCON + BM - 1) / BM, 256, 0, stream>>>(
            xin + (size_t)NPAT * H, H, H, aggn0, H, H, Wroot_l, Wrel_l0, br,
            xout + (size_t)NPAT * H, NCON, 1);

        xin = xout;
        xout = x0;
    }
    // final result currently in x0 -> copy to d_out
    hipMemcpyAsync(out, x0, (size_t)NN * H * 4, hipMemcpyDeviceToDevice, stream);
}

// Round 2
// 654.728 us; speedup vs baseline: 1.2304x; 1.2304x over previous
//
#include <hip/hip_runtime.h>
#include <hip/hip_bf16.h>

#define NPAT 50000
#define NCON 20000
#define NN   70000
#define EE   800000
#define H    128

// ============ CSR build ============

// histogram over both relations; segment id = dst_pc (rel0, concepts 0..NCON)
// or NCON + dst_cp (rel1, patients)
__global__ void hist2_kernel(const int* __restrict__ dst_pc, const int* __restrict__ dst_cp,
                             int* __restrict__ deg) {
    int i = blockIdx.x * blockDim.x + threadIdx.x;
    if (i < EE) atomicAdd(&deg[dst_pc[i]], 1);
    else if (i < 2 * EE) atomicAdd(&deg[NCON + dst_cp[i - EE]], 1);
}

// multi-block exclusive scan, stage 1: per-block scan of 1024 elems (256 thr x 4)
__global__ __launch_bounds__(256) void scan_blk_kernel(const int* __restrict__ deg, int n,
                                                       int* __restrict__ start,
                                                       int* __restrict__ bsum) {
    int b = blockIdx.x, t = threadIdx.x;
    int base = b * 1024 + t * 4;
    int4 d = make_int4(0, 0, 0, 0);
    if (base + 3 < n) d = *(const int4*)&deg[base];
    else {
        if (base     < n) d.x = deg[base];
        if (base + 1 < n) d.y = deg[base + 1];
        if (base + 2 < n) d.z = deg[base + 2];
        if (base + 3 < n) d.w = deg[base + 3];
    }
    int s = d.x + d.y + d.z + d.w;
    __shared__ int sm[256];
    sm[t] = s;
    __syncthreads();
    for (int o = 1; o < 256; o <<= 1) {
        int v = (t >= o) ? sm[t - o] : 0;
        __syncthreads();
        sm[t] += v;
        __syncthreads();
    }
    int p = sm[t] - s;  // exclusive prefix within block
    if (t == 255) bsum[b] = sm[255];
    int e0 = p, e1 = p + d.x, e2 = e1 + d.y, e3 = e2 + d.z;
    if (base     < n) start[base]     = e0;
    if (base + 1 < n) start[base + 1] = e1;
    if (base + 2 < n) start[base + 2] = e2;
    if (base + 3 < n) start[base + 3] = e3;
}

// stage 2: single block scans block sums (nb <= 128)
__global__ void scan_mid_kernel(int* __restrict__ bsum, int nb) {
    __shared__ int sm[128];
    int t = threadIdx.x;
    int v = (t < nb) ? bsum[t] : 0;
    sm[t] = v;
    __syncthreads();
    for (int o = 1; o < 128; o <<= 1) {
        int u = (t >= o) ? sm[t - o] : 0;
        __syncthreads();
        sm[t] += u;
        __syncthreads();
    }
    if (t < nb) bsum[t] = sm[t] - v;  // exclusive
}

// stage 3: add block prefix; also materialize cur[] (atomic cursors) and sentinel
__global__ __launch_bounds__(256) void scan_add_kernel(int* __restrict__ start,
                                                       int* __restrict__ cur,
                                                       const int* __restrict__ bsum,
                                                       int n, int total) {
    int b = blockIdx.x, t = threadIdx.x;
    int base = b * 1024 + t * 4;
    int add = bsum[b];
#pragma unroll
    for (int q = 0; q < 4; q++) {
        int i = base + q;
        if (i < n) { int v = start[i] + add; start[i] = v; cur[i] = v; }
    }
    if (b == 0 && t == 0) start[n] = total;
}

__global__ void fill2_kernel(const int* __restrict__ dst_pc, const int* __restrict__ src_pc,
                             const int* __restrict__ dst_cp, const int* __restrict__ src_cp,
                             int* __restrict__ cur, int* __restrict__ esrc) {
    int i = blockIdx.x * blockDim.x + threadIdx.x;
    if (i < EE) {
        int p = atomicAdd(&cur[dst_pc[i]], 1);
        esrc[p] = src_pc[i];
    } else if (i < 2 * EE) {
        int j = i - EE;
        int p = atomicAdd(&cur[NCON + dst_cp[j]], 1);
        esrc[p] = src_cp[j];
    }
}

// ============ mean aggregation: one wave per dst segment ============
// segments 0..NCON-1: rel0 (p->c), src indices are global patient rows (base xin)
// segments NCON..NN-1: rel1 (c->p), src indices are concept-local (base xin+NPAT*H)
__global__ __launch_bounds__(64) void aggregate_kernel(
        const float* __restrict__ xin, const int* __restrict__ start,
        const int* __restrict__ esrc, float* __restrict__ aggn) {
    int d = blockIdx.x;
    int beg = start[d], end = start[d + 1];
    const float* base = (d < NCON) ? xin : xin + (size_t)NPAT * H;
    int c = threadIdx.x;  // cols 2c, 2c+1
    float2 a0 = {0.f, 0.f}, a1 = {0.f, 0.f}, a2 = {0.f, 0.f}, a3 = {0.f, 0.f};
    int j = beg;
    for (; j + 3 < end; j += 4) {
        int s0 = esrc[j], s1 = esrc[j + 1], s2 = esrc[j + 2], s3 = esrc[j + 3];
        float2 v0 = *(const float2*)&base[(size_t)s0 * H + 2 * c];
        float2 v1 = *(const float2*)&base[(size_t)s1 * H + 2 * c];
        float2 v2 = *(const float2*)&base[(size_t)s2 * H + 2 * c];
        float2 v3 = *(const float2*)&base[(size_t)s3 * H + 2 * c];
        a0.x += v0.x; a0.y += v0.y;
        a1.x += v1.x; a1.y += v1.y;
        a2.x += v2.x; a2.y += v2.y;
        a3.x += v3.x; a3.y += v3.y;
    }
    for (; j < end; j++) {
        int s = esrc[j];
        float2 v = *(const float2*)&base[(size_t)s * H + 2 * c];
        a0.x += v.x; a0.y += v.y;
    }
    float inv = 1.0f / (float)max(end - beg, 1);
    float2 o;
    o.x = (a0.x + a1.x + a2.x + a3.x) * inv;
    o.y = (a0.y + a1.y + a2.y + a3.y) * inv;
    *(float2*)&aggn[(size_t)d * H + 2 * c] = o;
}

// ============ fused fp32 GEMM: C = [A1 | A2] @ [B1 ; B2] + bias, opt relu ============
// BM=128 rows/block, BN=128(=H), BK=8; 256 threads, 8x8 microtile.
// Dual-job launch: blocks [0,nb0) run job0, rest job1 (wave-uniform branch).
#define BM 128
#define BK 8

struct GemmJob {
    const float* A1; const float* A2;
    const float* B1; const float* B2;
    const float* bias; float* C;
    int lda1, K1, lda2, K2, M, relu;
};

__global__ void gemm_dual_kernel(GemmJob j0, GemmJob j1, int nb0) {
    __shared__ float sA[BK][BM];
    __shared__ float sB[BK][H];
    bool first = (int)blockIdx.x < nb0;
    GemmJob j = first ? j0 : j1;
    int bm = (first ? blockIdx.x : blockIdx.x - nb0) * BM;
    int tid = threadIdx.x;
    int am = tid >> 1;
    int ak = (tid & 1) * 4;
    int bk = tid >> 5;
    int bn = (tid & 31) * 4;
    int ty = tid >> 4;
    int tx = tid & 15;
    float acc[8][8] = {};
    int Ktot = j.K1 + j.K2;
    for (int k0 = 0; k0 < Ktot; k0 += BK) {
        const float* As; int ldA; int kk; const float* Bs;
        if (k0 < j.K1) { As = j.A1; ldA = j.lda1; kk = k0;        Bs = j.B1 + (size_t)k0 * H; }
        else           { As = j.A2; ldA = j.lda2; kk = k0 - j.K1; Bs = j.B2 + (size_t)(k0 - j.K1) * H; }
        int gm = bm + am; if (gm >= j.M) gm = j.M - 1;
        float4 av = *(const float4*)&As[(size_t)gm * ldA + kk + ak];
        float4 bv = *(const float4*)&Bs[bk * H + bn];
        __syncthreads();
        sA[ak + 0][am] = av.x; sA[ak + 1][am] = av.y;
        sA[ak + 2][am] = av.z; sA[ak + 3][am] = av.w;
        *(float4*)&sB[bk][bn] = bv;
        __syncthreads();
#pragma unroll
        for (int k = 0; k < BK; k++) {
            float a[8], b[8];
            *(float4*)&a[0] = *(const float4*)&sA[k][ty * 8];
            *(float4*)&a[4] = *(const float4*)&sA[k][ty * 8 + 4];
            *(float4*)&b[0] = *(const float4*)&sB[k][tx * 4];
            *(float4*)&b[4] = *(const float4*)&sB[k][64 + tx * 4];
#pragma unroll
            for (int i = 0; i < 8; i++)
#pragma unroll
                for (int jj = 0; jj < 8; jj++)
                    acc[i][jj] += a[i] * b[jj];
        }
    }
    float bcol[8];
    *(float4*)&bcol[0] = *(const float4*)&j.bias[tx * 4];
    *(float4*)&bcol[4] = *(const float4*)&j.bias[64 + tx * 4];
#pragma unroll
    for (int i = 0; i < 8; i++) {
        int gr = bm + ty * 8 + i;
        if (gr < j.M) {
            float4 o1, o2;
            o1.x = acc[i][0] + bcol[0]; o1.y = acc[i][1] + bcol[1];
            o1.z = acc[i][2] + bcol[2]; o1.w = acc[i][3] + bcol[3];
            o2.x = acc[i][4] + bcol[4]; o2.y = acc[i][5] + bcol[5];
            o2.z = acc[i][6] + bcol[6]; o2.w = acc[i][7] + bcol[7];
            if (j.relu) {
                o1.x = fmaxf(o1.x, 0.f); o1.y = fmaxf(o1.y, 0.f);
                o1.z = fmaxf(o1.z, 0.f); o1.w = fmaxf(o1.w, 0.f);
                o2.x = fmaxf(o2.x, 0.f); o2.y = fmaxf(o2.y, 0.f);
                o2.z = fmaxf(o2.z, 0.f); o2.w = fmaxf(o2.w, 0.f);
            }
            *(float4*)&j.C[(size_t)gr * H + tx * 4] = o1;
            *(float4*)&j.C[(size_t)gr * H + 64 + tx * 4] = o2;
        }
    }
}

// ============ launch ============

extern "C" void kernel_launch(void* const* d_in, const int* in_sizes, int n_in,
                              void* d_out, int out_size, void* d_ws, size_t ws_size,
                              hipStream_t stream) {
    const float* x_patient = (const float*)d_in[0];
    const float* x_concept = (const float*)d_in[1];
    const float* W_p       = (const float*)d_in[2];
    const float* b_p       = (const float*)d_in[3];
    const float* W_c       = (const float*)d_in[4];
    const float* b_c       = (const float*)d_in[5];
    const float* W_root    = (const float*)d_in[6];
    const float* b_root    = (const float*)d_in[7];
    const float* W_rel     = (const float*)d_in[8];
    const int*   src_pc    = (const int*)d_in[9];
    const int*   dst_pc    = (const int*)d_in[10];
    const int*   src_cp    = (const int*)d_in[11];
    const int*   dst_cp    = (const int*)d_in[12];
    float* out = (float*)d_out;

    char* w = (char*)d_ws;
    float* x0   = (float*)w; w += (size_t)NN * H * 4;   // 35.8 MB
    float* aggn = (float*)w; w += (size_t)NN * H * 4;   // 35.8 MB (concepts rows 0..NCON, patients after)
    int* deg   = (int*)w; w += (size_t)NN * 4;
    int* start = (int*)w; w += (size_t)(NN + 1) * 4;
    int* cur   = (int*)w; w += (size_t)NN * 4;
    int* bsum  = (int*)w; w += 256 * 4;
    int* esrc  = (int*)w; w += (size_t)2 * EE * 4;      // 6.4 MB

    const int NB_SCAN = (NN + 1023) / 1024;  // 69
    const int EB2 = (2 * EE + 255) / 256;    // 6250

    // ---- CSR build
    hipMemsetAsync(deg, 0, (size_t)NN * 4, stream);
    hist2_kernel<<<EB2, 256, 0, stream>>>(dst_pc, dst_cp, deg);
    scan_blk_kernel<<<NB_SCAN, 256, 0, stream>>>(deg, NN, start, bsum);
    scan_mid_kernel<<<1, 128, 0, stream>>>(bsum, NB_SCAN);
    scan_add_kernel<<<NB_SCAN, 256, 0, stream>>>(start, cur, bsum, NN, 2 * EE);
    fill2_kernel<<<EB2, 256, 0, stream>>>(dst_pc, src_pc, dst_cp, src_cp, cur, esrc);

    const int PB = (NPAT + BM - 1) / BM;  // 391
    const int CB = (NCON + BM - 1) / BM;  // 157

    // ---- projections -> x0
    {
        GemmJob jp = { x_patient, nullptr, W_p, nullptr, b_p, x0, 64, 64, 0, 0, NPAT, 0 };
        GemmJob jc = { x_concept, nullptr, W_c, nullptr, b_c, x0 + (size_t)NPAT * H,
                       128, 128, 0, 0, NCON, 0 };
        gemm_dual_kernel<<<PB + CB, 256, 0, stream>>>(jp, jc, PB);
    }

    // ---- layers (layer0 out -> d_out, layer1 out -> x0, final copy back)
    const float* xin = x0;
    float* xout = out;
    for (int l = 0; l < 2; l++) {
        aggregate_kernel<<<NN, 64, 0, stream>>>(xin, start, esrc, aggn);
        const float* Wroot_l = W_root + (size_t)l * H * H;
        const float* Wrel_l0 = W_rel + (size_t)(l * 2 + 0) * H * H;
        const float* Wrel_l1 = W_rel + (size_t)(l * 2 + 1) * H * H;
        const float* br = b_root + (size_t)l * H;
        GemmJob jp = { xin, aggn + (size_t)NCON * H, Wroot_l, Wrel_l1, br,
                       xout, H, H, H, H, NPAT, 1 };
        GemmJob jc = { xin + (size_t)NPAT * H, aggn, Wroot_l, Wrel_l0, br,
                       xout + (size_t)NPAT * H, H, H, H, H, NCON, 1 };
        gemm_dual_kernel<<<PB + CB, 256, 0, stream>>>(jp, jc, PB);
        xin = xout;
        xout = x0;
    }
    hipMemcpyAsync(out, x0, (size_t)NN * H * 4, hipMemcpyDeviceToDevice, stream);
}